// Round 16
// baseline (372.892 us; speedup 1.0000x reference)
//
#include <hip/hip_runtime.h>
#include <hip/hip_bf16.h>
#include <cstdint>

#define NND 100000
#define NT 4
#define NE 150000
#define TOTE (NT * NE)
#define HID 128
#define NHD 8
#define MS 128
#define SEL ((size_t)NND * MS)   // elements per projection buffer
#define BAT 8                    // gather batch in k_edge
#define PNW 32                   // nodes per wave in k_projF

typedef __bf16 bf16x8 __attribute__((ext_vector_type(8)));
typedef float f32x4 __attribute__((ext_vector_type(4)));
typedef unsigned int u32x4 __attribute__((ext_vector_type(4)));  // native vec for nt-store

__device__ __forceinline__ float bf2f(unsigned int u16) {
  unsigned int b = u16 << 16;
  return __builtin_bit_cast(float, b);
}
__device__ __forceinline__ unsigned short f2bf(float f) {
  unsigned int b = __builtin_bit_cast(unsigned int, f);
  b += 0x7FFFu + ((b >> 16) & 1u);
  return (unsigned short)(b >> 16);
}

// ---- pack weights into MFMA A-fragment order (bf16) ----
__global__ void k_pack_w(const float* __restrict__ Wq, const float* __restrict__ Wk,
                         const float* __restrict__ Wm, unsigned short* __restrict__ wp) {
  int p = blockIdx.x * 256 + threadIdx.x;
  int e    = p & 7;
  int lane = (p >> 3) & 63;
  int b    = (p >> 9) & 3;
  int c    = (p >> 11) & 7;
  int kind = (p >> 14) & 3;
  int t    = p >> 16;
  int col = c * 16 + (lane & 15);
  int k   = b * 32 + (lane >> 4) * 8 + e;
  float v;
  if (kind == 0)      v = 0.25f * Wq[((size_t)t * HID + k) * MS + col];
  else if (kind == 1) v = Wk[((size_t)t * HID + k) * MS + col];
  else if (kind == 2) v = Wm[((size_t)t * 2 * HID + k) * MS + col];
  else                v = Wm[((size_t)t * 2 * HID + HID + k) * MS + col];
  wp[p] = f2bf(v);
}

// ---- CSR build (window-local): key = win*NND + tgt, win = type >> tshift ----
__global__ void k_hist(const int* __restrict__ adj, int* __restrict__ counts, int tshift) {
  int i = blockIdx.x * 256 + threadIdx.x;
  if (i < TOTE) {
    int win = (i / NE) >> tshift;
    atomicAdd(&counts[win * NND + adj[2 * i + 1]], 1);
  }
}

__global__ void k_blocksum(const int* __restrict__ counts, int* __restrict__ bsum, int ntot) {
  __shared__ int s[4];
  int i = blockIdx.x * 256 + threadIdx.x;
  int v = (i < ntot) ? counts[i] : 0;
#pragma unroll
  for (int d = 1; d < 64; d <<= 1) v += __shfl_xor(v, d);
  if ((threadIdx.x & 63) == 0) s[threadIdx.x >> 6] = v;
  __syncthreads();
  if (threadIdx.x == 0) bsum[blockIdx.x] = s[0] + s[1] + s[2] + s[3];
}

// single block of 1024: exclusive scan of bsum[0..nb), nb <= 1024
__global__ void k_scan_mid(int* __restrict__ bsum, int nb, int* __restrict__ offsets,
                           int ntot) {
  __shared__ int s[1024];
  int t = threadIdx.x;
  s[t] = (t < nb) ? bsum[t] : 0;
  __syncthreads();
  for (int d = 1; d < 1024; d <<= 1) {
    int u = (t >= d) ? s[t - d] : 0;
    __syncthreads();
    s[t] += u;
    __syncthreads();
  }
  if (t < nb) bsum[t] = (t > 0) ? s[t - 1] : 0;
  if (t == 0) offsets[ntot] = TOTE;
}

__global__ void k_scan_add(const int* __restrict__ counts, const int* __restrict__ bsum,
                           int* __restrict__ offsets, int* __restrict__ cursor, int ntot) {
  __shared__ int s[256];
  int b = blockIdx.x, t = threadIdx.x, i = b * 256 + t;
  s[t] = (i < ntot) ? counts[i] : 0;
  __syncthreads();
  for (int d = 1; d < 256; d <<= 1) {
    int u = (t >= d) ? s[t - d] : 0;
    __syncthreads();
    s[t] += u;
    __syncthreads();
  }
  int excl = ((t > 0) ? s[t - 1] : 0) + bsum[b];
  if (i < ntot) { offsets[i] = excl; cursor[i] = excl; }
}

// edata payload pre-encoded: (rel << 24) | (rel*NND + src), rel = window-local type
__global__ void k_scatter(const int* __restrict__ adj, int* __restrict__ cursor,
                          int* __restrict__ edata, int tshift) {
  int i = blockIdx.x * 256 + threadIdx.x;
  if (i >= TOTE) return;
  int src = adj[2 * i], tgt = adj[2 * i + 1];
  int t = i / NE;
  int win = t >> tshift;
  int rel = t & ((1 << tshift) - 1);
  int pos = atomicAdd(&cursor[win * NND + tgt], 1);
  edata[pos] = (rel << 24) | (rel * NND + src);
}

// ---- projection, XCD-swizzled pass-parallel, 32 KB LDS-staged weights ----
// Reads x directly as f32 (no xb staging buffer; r4-validated path).
// kind==3 (Mt) folds bm into the stored rows. Non-temporal output stores.
__global__ __launch_bounds__(256) void k_projF(const float* __restrict__ x,
                                               const unsigned short* __restrict__ wp,
                                               const float* __restrict__ bm,
                                               unsigned short* __restrict__ bQ,
                                               unsigned short* __restrict__ bK,
                                               unsigned short* __restrict__ bMs,
                                               unsigned short* __restrict__ bMt,
                                               int tlo, int npass, int cpx) {
  __shared__ unsigned short wlds[16384];  // 32 KB: weights, then epilogue overlay
  int flat = blockIdx.x;
  int xcd = flat & 7;
  int idx = flat >> 3;
  int chunk = xcd * cpx + idx / npass;
  int pass  = idx - (idx / npass) * npass;
  if (chunk * 128 >= NND) return;
  int tt = pass >> 2, kind = pass & 3;
  int wave = threadIdx.x >> 6;
  int lane = threadIdx.x & 63;
  int la = lane & 15, kg = lane >> 4;
  int nodeBase = chunk * 128 + wave * PNW;

  // issue weight DMA: 8 KB per wave, 1 KB per instruction, linear
  {
    const char* gsrc = (const char*)(wp + (size_t)((tlo + tt) * 4 + kind) * 16384) +
                       wave * 8192 + lane * 16;
    char* ldst = (char*)wlds + wave * 8192;
#pragma unroll
    for (int i = 0; i < 8; i++) {
      __builtin_amdgcn_global_load_lds(
          (const __attribute__((address_space(1))) unsigned int*)(gsrc + i * 1024),
          (__attribute__((address_space(3))) unsigned int*)(ldst + i * 1024), 16, 0, 0);
    }
  }

  // x fragments for both 16-node groups (f32 -> bf16, rows L2-hot across passes)
  bf16x8 xf[2][4];
#pragma unroll
  for (int g = 0; g < 2; g++) {
    int node = nodeBase + g * 16 + la;
    if (node < NND) {
      const float* xp = x + (size_t)node * HID + kg * 8;
#pragma unroll
      for (int b = 0; b < 4; b++) {
        float4 v0 = *reinterpret_cast<const float4*>(xp + b * 32);
        float4 v1 = *reinterpret_cast<const float4*>(xp + b * 32 + 4);
        bf16x8 f;
        f[0] = (__bf16)v0.x; f[1] = (__bf16)v0.y; f[2] = (__bf16)v0.z; f[3] = (__bf16)v0.w;
        f[4] = (__bf16)v1.x; f[5] = (__bf16)v1.y; f[6] = (__bf16)v1.z; f[7] = (__bf16)v1.w;
        xf[g][b] = f;
      }
    } else {
#pragma unroll
      for (int b = 0; b < 4; b++)
#pragma unroll
        for (int e = 0; e < 8; e++) xf[g][b][e] = (__bf16)0.0f;
    }
  }

  asm volatile("s_waitcnt vmcnt(0)");
  __syncthreads();

  f32x4 acc[2][8];
#pragma unroll
  for (int g = 0; g < 2; g++)
#pragma unroll
    for (int c = 0; c < 8; c++)
#pragma unroll
      for (int r = 0; r < 4; r++) acc[g][c][r] = 0.0f;

#pragma unroll
  for (int c = 0; c < 8; c++)
#pragma unroll
    for (int b = 0; b < 4; b++) {
      bf16x8 wf = *reinterpret_cast<const bf16x8*>(wlds + (c * 4 + b) * 512 + lane * 8);
      acc[0][c] = __builtin_amdgcn_mfma_f32_16x16x32_bf16(wf, xf[0][b], acc[0][c], 0, 0, 0);
      acc[1][c] = __builtin_amdgcn_mfma_f32_16x16x32_bf16(wf, xf[1][b], acc[1][c], 0, 0, 0);
    }

  __syncthreads();  // all waves done reading weights; overlay epilogue tile

  unsigned short* ob =
      (kind == 0 ? bQ : kind == 1 ? bK : kind == 2 ? bMs : bMt) + (size_t)tt * SEL;
  const float* bmrow = bm + (size_t)(tlo + tt) * MS;
  bool addb = (kind == 3);
#pragma unroll
  for (int g = 0; g < 2; g++) {
    char* rowp = (char*)wlds + (size_t)(wave * 32 + g * 16 + la) * 256;
    int sw = (la & 7) << 5;
#pragma unroll
    for (int c = 0; c < 8; c++) {
      float b0 = 0.f, b1 = 0.f, b2 = 0.f, b3 = 0.f;
      if (addb) {
        float4 bb = *reinterpret_cast<const float4*>(bmrow + c * 16 + kg * 4);
        b0 = bb.x; b1 = bb.y; b2 = bb.z; b3 = bb.w;
      }
      uint2 o;
      o.x = (unsigned int)f2bf(acc[g][c][0] + b0) |
            ((unsigned int)f2bf(acc[g][c][1] + b1) << 16);
      o.y = (unsigned int)f2bf(acc[g][c][2] + b2) |
            ((unsigned int)f2bf(acc[g][c][3] + b3) << 16);
      *reinterpret_cast<uint2*>(rowp + ((c * 32 + kg * 8) ^ sw)) = o;
    }
  }
#pragma unroll
  for (int p = 0; p < 8; p++) {
    int nidx = p * 4 + kg;
    int node = nodeBase + nidx;
    char* rp = (char*)wlds + (size_t)(wave * 32 + nidx) * 256;
    u32x4 v = *reinterpret_cast<u32x4*>(rp + ((la * 16) ^ ((nidx & 7) << 5)));
    if (node < NND)
      __builtin_nontemporal_store(
          v, reinterpret_cast<u32x4*>(ob + (size_t)node * MS + la * 8));
  }
}

// ---- fused edge pass: FOUR consecutive nodes per wave (contiguous CSR range) ----
// Range [offs[n0], offs[n0+4]) with scalar splits m1..m3. ~24 outstanding
// gathers per wave; node routing = nested wave-uniform scalar branches.
template <int NTP>
__global__ __launch_bounds__(256) void k_edge(const int* __restrict__ edata,
                                              const int* __restrict__ offs,
                                              const unsigned short* __restrict__ qall,
                                              const unsigned short* __restrict__ kall,
                                              const unsigned short* __restrict__ msall,
                                              const unsigned short* __restrict__ mtall,
                                              float* __restrict__ out,
                                              float* __restrict__ denom,
                                              int init, int fin) {
  int wave = threadIdx.x >> 6, lane = threadIdx.x & 63;
  int n0 = (blockIdx.x * 4 + wave) * 4;
  if (n0 >= NND) return;
  int beg = __builtin_amdgcn_readfirstlane(offs[n0]);
  int m1  = __builtin_amdgcn_readfirstlane(offs[n0 + 1]);
  int m2  = __builtin_amdgcn_readfirstlane(offs[n0 + 2]);
  int m3  = __builtin_amdgcn_readfirstlane(offs[n0 + 3]);
  int end = __builtin_amdgcn_readfirstlane(offs[n0 + 4]);
  int h = lane >> 3;

  float ds[4] = {0.f, 0.f, 0.f, 0.f};
  float ma[4] = {0.f, 0.f, 0.f, 0.f};
  float mb[4] = {0.f, 0.f, 0.f, 0.f};

  if (beg < end) {
    unsigned int qv[4][NTP], mt[4][NTP];
#pragma unroll
    for (int v = 0; v < 4; v++)
#pragma unroll
      for (int tt = 0; tt < NTP; tt++) {
        qv[v][tt] = *reinterpret_cast<const unsigned int*>(
            qall + ((size_t)tt * NND + n0 + v) * MS + lane * 2);
        mt[v][tt] = *reinterpret_cast<const unsigned int*>(
            mtall + ((size_t)tt * NND + n0 + v) * MS + lane * 2);
      }

    for (int base = beg; base < end; base += BAT) {
      int ed[BAT];
      unsigned int ku[BAT], mu[BAT];
#pragma unroll
      for (int j = 0; j < BAT; j++) {
        int p = base + j;
        ed[j] = (p < end) ? __builtin_amdgcn_readfirstlane(edata[p]) : -1;
      }
#pragma unroll
      for (int j = 0; j < BAT; j++) {
        if (ed[j] >= 0) {  // scalar compare + branch
          int row = ed[j] & 0xFFFFFF;  // rel*NND + src, scalar
          ku[j] = *reinterpret_cast<const unsigned int*>(kall  + (size_t)row * MS + lane * 2);
          mu[j] = *reinterpret_cast<const unsigned int*>(msall + (size_t)row * MS + lane * 2);
        }
      }
#pragma unroll
      for (int j = 0; j < BAT; j++) {
        if (ed[j] >= 0) {
          int rel = ed[j] >> 24;  // scalar
          int p = base + j;       // scalar
          unsigned int qu, mtu;
          // route node registers: nested wave-uniform branches, static indices
          if (p < m2) {
            if (p < m1) {
              if constexpr (NTP == 2) { qu = rel ? qv[0][1] : qv[0][0]; mtu = rel ? mt[0][1] : mt[0][0]; }
              else { qu = rel==0?qv[0][0]:rel==1?qv[0][1]:rel==2?qv[0][2]:qv[0][3];
                     mtu = rel==0?mt[0][0]:rel==1?mt[0][1]:rel==2?mt[0][2]:mt[0][3]; }
            } else {
              if constexpr (NTP == 2) { qu = rel ? qv[1][1] : qv[1][0]; mtu = rel ? mt[1][1] : mt[1][0]; }
              else { qu = rel==0?qv[1][0]:rel==1?qv[1][1]:rel==2?qv[1][2]:qv[1][3];
                     mtu = rel==0?mt[1][0]:rel==1?mt[1][1]:rel==2?mt[1][2]:mt[1][3]; }
            }
          } else {
            if (p < m3) {
              if constexpr (NTP == 2) { qu = rel ? qv[2][1] : qv[2][0]; mtu = rel ? mt[2][1] : mt[2][0]; }
              else { qu = rel==0?qv[2][0]:rel==1?qv[2][1]:rel==2?qv[2][2]:qv[2][3];
                     mtu = rel==0?mt[2][0]:rel==1?mt[2][1]:rel==2?mt[2][2]:mt[2][3]; }
            } else {
              if constexpr (NTP == 2) { qu = rel ? qv[3][1] : qv[3][0]; mtu = rel ? mt[3][1] : mt[3][0]; }
              else { qu = rel==0?qv[3][0]:rel==1?qv[3][1]:rel==2?qv[3][2]:qv[3][3];
                     mtu = rel==0?mt[3][0]:rel==1?mt[3][1]:rel==2?mt[3][2]:mt[3][3]; }
            }
          }
          float part = bf2f(qu & 0xFFFFu) * bf2f(ku[j] & 0xFFFFu) +
                       bf2f(qu >> 16) * bf2f(ku[j] >> 16);
          part += __shfl_xor(part, 1);
          part += __shfl_xor(part, 2);
          part += __shfl_xor(part, 4);
          // scores are O(+-5) worst-case: softmax max-shift provably unnecessary in f32
          float ev = __expf(part);
          float a0 = bf2f(mu[j] & 0xFFFFu) + bf2f(mtu & 0xFFFFu);  // bm folded into Mt
          float a1 = bf2f(mu[j] >> 16) + bf2f(mtu >> 16);
          float w0 = ev * fmaxf(a0, 0.f);
          float w1 = ev * fmaxf(a1, 0.f);
          if (p < m2) {
            if (p < m1) { ds[0] += ev; ma[0] += w0; mb[0] += w1; }
            else        { ds[1] += ev; ma[1] += w0; mb[1] += w1; }
          } else {
            if (p < m3) { ds[2] += ev; ma[2] += w0; mb[2] += w1; }
            else        { ds[3] += ev; ma[3] += w0; mb[3] += w1; }
          }
        }
      }
    }
  }

#pragma unroll
  for (int v = 0; v < 4; v++) {
    int n = n0 + v;
    float dsum = ds[v], m0 = ma[v], m1v = mb[v];
    float* op = out + (size_t)n * MS + lane * 2;
    if (!init) {
      float2 prev = *reinterpret_cast<float2*>(op);
      m0 += prev.x; m1v += prev.y;
      dsum += denom[n * NHD + h];
    }
    if (fin) {
      float inv = dsum > 0.f ? 1.0f / dsum : 0.0f;
      float2 o; o.x = m0 * inv; o.y = m1v * inv;
      *reinterpret_cast<float2*>(op) = o;
    } else {
      float2 o; o.x = m0; o.y = m1v;
      *reinterpret_cast<float2*>(op) = o;
      if ((lane & 7) == 0) denom[n * NHD + h] = dsum;
    }
  }
}

extern "C" void kernel_launch(void* const* d_in, const int* in_sizes, int n_in,
                              void* d_out, int out_size, void* d_ws, size_t ws_size,
                              hipStream_t stream) {
  const float* x  = (const float*)d_in[0];
  const int* adj  = (const int*)d_in[1];
  const float* Wq = (const float*)d_in[2];
  const float* Wk = (const float*)d_in[3];
  const float* Wm = (const float*)d_in[4];
  const float* bm = (const float*)d_in[5];
  float* out = (float*)d_out;

  char* ws = (char*)d_ws;
  size_t off = 0;
  auto alloc = [&](size_t bytes) -> char* {
    char* p = ws + off;
    off += (bytes + 255) & ~(size_t)255;
    return p;
  };
  // slim fixed allocs (no xb) so TPH=4 fits if ws >= ~418 MB
  unsigned short* wp = (unsigned short*)alloc((size_t)NT * 4 * HID * MS * 2);  // 0.5 MB
  int* counts   = (int*)alloc((size_t)2 * NND * 4);                            // max 2 windows
  int* offsets  = (int*)alloc((size_t)(2 * NND + 1) * 4);
  int* cursor   = (int*)alloc((size_t)2 * NND * 4);
  int* bsum     = (int*)alloc(1024 * 4);
  int* edata    = (int*)alloc((size_t)TOTE * 4);                               // 2.4 MB
  float* denom  = (float*)alloc((size_t)NND * NHD * 4);                        // 3.2 MB

  size_t avail = (ws_size > off) ? (ws_size - off) : 0;
  const size_t perType = 4 * SEL * 2;  // Q,K,Ms,Mt for one type = 102.4 MB
  int TPH = (avail >= 4 * perType) ? 4 : 2;
  int tshift = (TPH == 4) ? 2 : 1;
  int NWIN = NT / TPH;
  int ntot = NWIN * NND;
  unsigned short* region = (unsigned short*)(ws + off);
  unsigned short* bufQ  = region;
  unsigned short* bufK  = region + (size_t)TPH * SEL;
  unsigned short* bufMs = region + (size_t)2 * TPH * SEL;
  unsigned short* bufMt = region + (size_t)3 * TPH * SEL;

  hipMemsetAsync(counts, 0, (size_t)ntot * 4, stream);

  k_pack_w<<<(NT * 4 * HID * MS) / 256, 256, 0, stream>>>(Wq, Wk, Wm, wp);

  const int NBS = (ntot + 255) / 256;  // <= 782, fits 1024-thread scan_mid
  k_hist<<<(TOTE + 255) / 256, 256, 0, stream>>>(adj, counts, tshift);
  k_blocksum<<<NBS, 256, 0, stream>>>(counts, bsum, ntot);
  k_scan_mid<<<1, 1024, 0, stream>>>(bsum, NBS, offsets, ntot);
  k_scan_add<<<NBS, 256, 0, stream>>>(counts, bsum, offsets, cursor, ntot);
  k_scatter<<<(TOTE + 255) / 256, 256, 0, stream>>>(adj, cursor, edata, tshift);

  const int nchunks = (NND + 127) / 128;   // 782
  const int cpx = (nchunks + 7) / 8;       // 98 chunks per XCD
  const int ngrid4 = (NND / 4 + 3) / 4;    // 6250 (4 nodes per wave)

  for (int w = 0; w < NWIN; w++) {
    int tlo = w * TPH;
    int npass = TPH * 4;
    int pgrid = 8 * cpx * npass;
    k_projF<<<pgrid, 256, 0, stream>>>(x, wp, bm, bufQ, bufK, bufMs, bufMt,
                                       tlo, npass, cpx);
    if (TPH == 2)
      k_edge<2><<<ngrid4, 256, 0, stream>>>(edata, offsets + (size_t)w * NND,
                                            bufQ, bufK, bufMs, bufMt, out, denom,
                                            w == 0 ? 1 : 0, (w == NWIN - 1) ? 1 : 0);
    else
      k_edge<4><<<ngrid4, 256, 0, stream>>>(edata, offsets + (size_t)w * NND,
                                            bufQ, bufK, bufMs, bufMt, out, denom,
                                            w == 0 ? 1 : 0, (w == NWIN - 1) ? 1 : 0);
  }
}

// Round 17
// 318.533 us; speedup vs baseline: 1.1707x; 1.1707x over previous
//
#include <hip/hip_runtime.h>
#include <hip/hip_bf16.h>
#include <cstdint>

#define NND 100000
#define NT 4
#define NE 150000
#define TOTE (NT * NE)
#define HID 128
#define NHD 8
#define MS 128
#define SEL ((size_t)NND * MS)   // elements per projection buffer
#define BAT 8                    // gather batch in k_edge
#define PNW 32                   // nodes per wave in k_projF

typedef __bf16 bf16x8 __attribute__((ext_vector_type(8)));
typedef float f32x4 __attribute__((ext_vector_type(4)));
typedef unsigned int u32x4 __attribute__((ext_vector_type(4)));  // native vec for nt-store

__device__ __forceinline__ float bf2f(unsigned int u16) {
  unsigned int b = u16 << 16;
  return __builtin_bit_cast(float, b);
}
__device__ __forceinline__ unsigned short f2bf(float f) {
  unsigned int b = __builtin_bit_cast(unsigned int, f);
  b += 0x7FFFu + ((b >> 16) & 1u);
  return (unsigned short)(b >> 16);
}

// ---- x -> bf16 ----
__global__ void k_convert_x(const float* __restrict__ x, unsigned short* __restrict__ xb) {
  int i = (blockIdx.x * 256 + threadIdx.x) * 4;
  float4 v = *reinterpret_cast<const float4*>(x + i);
  ushort4 o;
  o.x = f2bf(v.x); o.y = f2bf(v.y); o.z = f2bf(v.z); o.w = f2bf(v.w);
  *reinterpret_cast<ushort4*>(xb + i) = o;
}

// ---- pack weights into MFMA A-fragment order (bf16) ----
__global__ void k_pack_w(const float* __restrict__ Wq, const float* __restrict__ Wk,
                         const float* __restrict__ Wm, unsigned short* __restrict__ wp) {
  int p = blockIdx.x * 256 + threadIdx.x;
  int e    = p & 7;
  int lane = (p >> 3) & 63;
  int b    = (p >> 9) & 3;
  int c    = (p >> 11) & 7;
  int kind = (p >> 14) & 3;
  int t    = p >> 16;
  int col = c * 16 + (lane & 15);
  int k   = b * 32 + (lane >> 4) * 8 + e;
  float v;
  if (kind == 0)      v = 0.25f * Wq[((size_t)t * HID + k) * MS + col];
  else if (kind == 1) v = Wk[((size_t)t * HID + k) * MS + col];
  else if (kind == 2) v = Wm[((size_t)t * 2 * HID + k) * MS + col];
  else                v = Wm[((size_t)t * 2 * HID + HID + k) * MS + col];
  wp[p] = f2bf(v);
}

// ---- CSR build (window-local): key = win*NND + tgt, win = type >> tshift ----
__global__ void k_hist(const int* __restrict__ adj, int* __restrict__ counts, int tshift) {
  int i = blockIdx.x * 256 + threadIdx.x;
  if (i < TOTE) {
    int win = (i / NE) >> tshift;
    atomicAdd(&counts[win * NND + adj[2 * i + 1]], 1);
  }
}

__global__ void k_blocksum(const int* __restrict__ counts, int* __restrict__ bsum, int ntot) {
  __shared__ int s[4];
  int i = blockIdx.x * 256 + threadIdx.x;
  int v = (i < ntot) ? counts[i] : 0;
#pragma unroll
  for (int d = 1; d < 64; d <<= 1) v += __shfl_xor(v, d);
  if ((threadIdx.x & 63) == 0) s[threadIdx.x >> 6] = v;
  __syncthreads();
  if (threadIdx.x == 0) bsum[blockIdx.x] = s[0] + s[1] + s[2] + s[3];
}

// single block of 1024: exclusive scan of bsum[0..nb), nb <= 1024
__global__ void k_scan_mid(int* __restrict__ bsum, int nb, int* __restrict__ offsets,
                           int ntot) {
  __shared__ int s[1024];
  int t = threadIdx.x;
  s[t] = (t < nb) ? bsum[t] : 0;
  __syncthreads();
  for (int d = 1; d < 1024; d <<= 1) {
    int u = (t >= d) ? s[t - d] : 0;
    __syncthreads();
    s[t] += u;
    __syncthreads();
  }
  if (t < nb) bsum[t] = (t > 0) ? s[t - 1] : 0;
  if (t == 0) offsets[ntot] = TOTE;
}

__global__ void k_scan_add(const int* __restrict__ counts, const int* __restrict__ bsum,
                           int* __restrict__ offsets, int* __restrict__ cursor, int ntot) {
  __shared__ int s[256];
  int b = blockIdx.x, t = threadIdx.x, i = b * 256 + t;
  s[t] = (i < ntot) ? counts[i] : 0;
  __syncthreads();
  for (int d = 1; d < 256; d <<= 1) {
    int u = (t >= d) ? s[t - d] : 0;
    __syncthreads();
    s[t] += u;
    __syncthreads();
  }
  int excl = ((t > 0) ? s[t - 1] : 0) + bsum[b];
  if (i < ntot) { offsets[i] = excl; cursor[i] = excl; }
}

// edata payload pre-encoded: (rel << 24) | (rel*NND + src), rel = window-local type
__global__ void k_scatter(const int* __restrict__ adj, int* __restrict__ cursor,
                          int* __restrict__ edata, int tshift) {
  int i = blockIdx.x * 256 + threadIdx.x;
  if (i >= TOTE) return;
  int src = adj[2 * i], tgt = adj[2 * i + 1];
  int t = i / NE;
  int win = t >> tshift;
  int rel = t & ((1 << tshift) - 1);
  int pos = atomicAdd(&cursor[win * NND + tgt], 1);
  edata[pos] = (rel << 24) | (rel * NND + src);
}

// ---- projection, XCD-swizzled pass-parallel, 32 KB LDS-staged weights (r12 config) ----
// kind==3 (Mt) folds bm into the stored rows. Non-temporal output stores.
__global__ __launch_bounds__(256) void k_projF(const unsigned short* __restrict__ xb,
                                               const unsigned short* __restrict__ wp,
                                               const float* __restrict__ bm,
                                               unsigned short* __restrict__ bQ,
                                               unsigned short* __restrict__ bK,
                                               unsigned short* __restrict__ bMs,
                                               unsigned short* __restrict__ bMt,
                                               int tlo, int npass, int cpx) {
  __shared__ unsigned short wlds[16384];  // 32 KB: weights, then epilogue overlay
  int flat = blockIdx.x;
  int xcd = flat & 7;
  int idx = flat >> 3;
  int chunk = xcd * cpx + idx / npass;
  int pass  = idx - (idx / npass) * npass;
  if (chunk * 128 >= NND) return;
  int tt = pass >> 2, kind = pass & 3;
  int wave = threadIdx.x >> 6;
  int lane = threadIdx.x & 63;
  int la = lane & 15, kg = lane >> 4;
  int nodeBase = chunk * 128 + wave * PNW;

  // issue weight DMA: 8 KB per wave, 1 KB per instruction, linear
  {
    const char* gsrc = (const char*)(wp + (size_t)((tlo + tt) * 4 + kind) * 16384) +
                       wave * 8192 + lane * 16;
    char* ldst = (char*)wlds + wave * 8192;
#pragma unroll
    for (int i = 0; i < 8; i++) {
      __builtin_amdgcn_global_load_lds(
          (const __attribute__((address_space(1))) unsigned int*)(gsrc + i * 1024),
          (__attribute__((address_space(3))) unsigned int*)(ldst + i * 1024), 16, 0, 0);
    }
  }

  // x fragments for both 16-node groups (L2-hot across the chunk's passes)
  bf16x8 xf[2][4];
#pragma unroll
  for (int g = 0; g < 2; g++) {
    int node = nodeBase + g * 16 + la;
    if (node < NND) {
      const unsigned short* ap = xb + (size_t)node * HID + kg * 8;
#pragma unroll
      for (int b = 0; b < 4; b++)
        xf[g][b] = *reinterpret_cast<const bf16x8*>(ap + b * 32);
    } else {
#pragma unroll
      for (int b = 0; b < 4; b++)
#pragma unroll
        for (int e = 0; e < 8; e++) xf[g][b][e] = (__bf16)0.0f;
    }
  }

  asm volatile("s_waitcnt vmcnt(0)");
  __syncthreads();

  f32x4 acc[2][8];
#pragma unroll
  for (int g = 0; g < 2; g++)
#pragma unroll
    for (int c = 0; c < 8; c++)
#pragma unroll
      for (int r = 0; r < 4; r++) acc[g][c][r] = 0.0f;

#pragma unroll
  for (int c = 0; c < 8; c++)
#pragma unroll
    for (int b = 0; b < 4; b++) {
      bf16x8 wf = *reinterpret_cast<const bf16x8*>(wlds + (c * 4 + b) * 512 + lane * 8);
      acc[0][c] = __builtin_amdgcn_mfma_f32_16x16x32_bf16(wf, xf[0][b], acc[0][c], 0, 0, 0);
      acc[1][c] = __builtin_amdgcn_mfma_f32_16x16x32_bf16(wf, xf[1][b], acc[1][c], 0, 0, 0);
    }

  __syncthreads();  // all waves done reading weights; overlay epilogue tile

  unsigned short* ob =
      (kind == 0 ? bQ : kind == 1 ? bK : kind == 2 ? bMs : bMt) + (size_t)tt * SEL;
  const float* bmrow = bm + (size_t)(tlo + tt) * MS;
  bool addb = (kind == 3);
#pragma unroll
  for (int g = 0; g < 2; g++) {
    char* rowp = (char*)wlds + (size_t)(wave * 32 + g * 16 + la) * 256;
    int sw = (la & 7) << 5;
#pragma unroll
    for (int c = 0; c < 8; c++) {
      float b0 = 0.f, b1 = 0.f, b2 = 0.f, b3 = 0.f;
      if (addb) {
        float4 bb = *reinterpret_cast<const float4*>(bmrow + c * 16 + kg * 4);
        b0 = bb.x; b1 = bb.y; b2 = bb.z; b3 = bb.w;
      }
      uint2 o;
      o.x = (unsigned int)f2bf(acc[g][c][0] + b0) |
            ((unsigned int)f2bf(acc[g][c][1] + b1) << 16);
      o.y = (unsigned int)f2bf(acc[g][c][2] + b2) |
            ((unsigned int)f2bf(acc[g][c][3] + b3) << 16);
      *reinterpret_cast<uint2*>(rowp + ((c * 32 + kg * 8) ^ sw)) = o;
    }
  }
#pragma unroll
  for (int p = 0; p < 8; p++) {
    int nidx = p * 4 + kg;
    int node = nodeBase + nidx;
    char* rp = (char*)wlds + (size_t)(wave * 32 + nidx) * 256;
    u32x4 v = *reinterpret_cast<u32x4*>(rp + ((la * 16) ^ ((nidx & 7) << 5)));
    if (node < NND)
      __builtin_nontemporal_store(
          v, reinterpret_cast<u32x4*>(ob + (size_t)node * MS + la * 8));
  }
}

// ---- fused edge pass: TWO consecutive nodes per wave (contiguous CSR range) ----
// Combined range [offs[n0], offs[n0+2]) with scalar split mid = offs[n0+1].
// Doubles outstanding gathers per wave; node routing is a wave-uniform branch.
template <int NTP>
__global__ __launch_bounds__(256) void k_edge(const int* __restrict__ edata,
                                              const int* __restrict__ offs,
                                              const unsigned short* __restrict__ qall,
                                              const unsigned short* __restrict__ kall,
                                              const unsigned short* __restrict__ msall,
                                              const unsigned short* __restrict__ mtall,
                                              float* __restrict__ out,
                                              float* __restrict__ denom,
                                              int init, int fin) {
  int wave = threadIdx.x >> 6, lane = threadIdx.x & 63;
  int n0 = (blockIdx.x * 4 + wave) * 2;
  if (n0 >= NND) return;
  int n1 = n0 + 1;
  int beg = __builtin_amdgcn_readfirstlane(offs[n0]);
  int mid = __builtin_amdgcn_readfirstlane(offs[n0 + 1]);
  int end = __builtin_amdgcn_readfirstlane(offs[n0 + 2]);
  int h = lane >> 3;

  float ds0 = 0.0f, m00 = 0.0f, m01 = 0.0f;
  float ds1 = 0.0f, m10 = 0.0f, m11 = 0.0f;

  if (beg < end) {
    unsigned int qv0[NTP], mt0[NTP], qv1[NTP], mt1[NTP];
#pragma unroll
    for (int tt = 0; tt < NTP; tt++) {
      qv0[tt] = *reinterpret_cast<const unsigned int*>(qall  + ((size_t)tt * NND + n0) * MS + lane * 2);
      mt0[tt] = *reinterpret_cast<const unsigned int*>(mtall + ((size_t)tt * NND + n0) * MS + lane * 2);
      qv1[tt] = *reinterpret_cast<const unsigned int*>(qall  + ((size_t)tt * NND + n1) * MS + lane * 2);
      mt1[tt] = *reinterpret_cast<const unsigned int*>(mtall + ((size_t)tt * NND + n1) * MS + lane * 2);
    }

    for (int base = beg; base < end; base += BAT) {
      int ed[BAT];
      unsigned int ku[BAT], mu[BAT];
#pragma unroll
      for (int j = 0; j < BAT; j++) {
        int p = base + j;
        ed[j] = (p < end) ? __builtin_amdgcn_readfirstlane(edata[p]) : -1;
      }
#pragma unroll
      for (int j = 0; j < BAT; j++) {
        if (ed[j] >= 0) {  // scalar compare + branch
          int row = ed[j] & 0xFFFFFF;  // rel*NND + src, scalar
          ku[j] = *reinterpret_cast<const unsigned int*>(kall  + (size_t)row * MS + lane * 2);
          mu[j] = *reinterpret_cast<const unsigned int*>(msall + (size_t)row * MS + lane * 2);
        }
      }
#pragma unroll
      for (int j = 0; j < BAT; j++) {
        if (ed[j] >= 0) {
          int rel = ed[j] >> 24;            // scalar
          bool first = (base + j) < mid;    // scalar: wave-uniform branch
          unsigned int qu, mtu;
          if (first) {
            if constexpr (NTP == 2) { qu = rel ? qv0[1] : qv0[0]; mtu = rel ? mt0[1] : mt0[0]; }
            else {
              qu  = rel == 0 ? qv0[0] : rel == 1 ? qv0[1] : rel == 2 ? qv0[2] : qv0[3];
              mtu = rel == 0 ? mt0[0] : rel == 1 ? mt0[1] : rel == 2 ? mt0[2] : mt0[3];
            }
          } else {
            if constexpr (NTP == 2) { qu = rel ? qv1[1] : qv1[0]; mtu = rel ? mt1[1] : mt1[0]; }
            else {
              qu  = rel == 0 ? qv1[0] : rel == 1 ? qv1[1] : rel == 2 ? qv1[2] : qv1[3];
              mtu = rel == 0 ? mt1[0] : rel == 1 ? mt1[1] : rel == 2 ? mt1[2] : mt1[3];
            }
          }
          float part = bf2f(qu & 0xFFFFu) * bf2f(ku[j] & 0xFFFFu) +
                       bf2f(qu >> 16) * bf2f(ku[j] >> 16);
          part += __shfl_xor(part, 1);
          part += __shfl_xor(part, 2);
          part += __shfl_xor(part, 4);
          // scores are O(+-5) worst-case: softmax max-shift provably unnecessary in f32
          float ev = __expf(part);
          float a0 = bf2f(mu[j] & 0xFFFFu) + bf2f(mtu & 0xFFFFu);  // bm folded into Mt
          float a1 = bf2f(mu[j] >> 16) + bf2f(mtu >> 16);
          float w0 = ev * fmaxf(a0, 0.f);
          float w1 = ev * fmaxf(a1, 0.f);
          if (first) { ds0 += ev; m00 += w0; m01 += w1; }
          else       { ds1 += ev; m10 += w0; m11 += w1; }
        }
      }
    }
  }

  // ---- node n0 output ----
  {
    float* op = out + (size_t)n0 * MS + lane * 2;
    if (!init) {
      float2 prev = *reinterpret_cast<float2*>(op);
      m00 += prev.x; m01 += prev.y;
      ds0 += denom[n0 * NHD + h];
    }
    if (fin) {
      float inv = ds0 > 0.f ? 1.0f / ds0 : 0.0f;
      float2 o; o.x = m00 * inv; o.y = m01 * inv;
      *reinterpret_cast<float2*>(op) = o;
    } else {
      float2 o; o.x = m00; o.y = m01;
      *reinterpret_cast<float2*>(op) = o;
      if ((lane & 7) == 0) denom[n0 * NHD + h] = ds0;
    }
  }
  // ---- node n1 output ----
  {
    float* op = out + (size_t)n1 * MS + lane * 2;
    if (!init) {
      float2 prev = *reinterpret_cast<float2*>(op);
      m10 += prev.x; m11 += prev.y;
      ds1 += denom[n1 * NHD + h];
    }
    if (fin) {
      float inv = ds1 > 0.f ? 1.0f / ds1 : 0.0f;
      float2 o; o.x = m10 * inv; o.y = m11 * inv;
      *reinterpret_cast<float2*>(op) = o;
    } else {
      float2 o; o.x = m10; o.y = m11;
      *reinterpret_cast<float2*>(op) = o;
      if ((lane & 7) == 0) denom[n1 * NHD + h] = ds1;
    }
  }
}

extern "C" void kernel_launch(void* const* d_in, const int* in_sizes, int n_in,
                              void* d_out, int out_size, void* d_ws, size_t ws_size,
                              hipStream_t stream) {
  const float* x  = (const float*)d_in[0];
  const int* adj  = (const int*)d_in[1];
  const float* Wq = (const float*)d_in[2];
  const float* Wk = (const float*)d_in[3];
  const float* Wm = (const float*)d_in[4];
  const float* bm = (const float*)d_in[5];
  float* out = (float*)d_out;

  char* ws = (char*)d_ws;
  size_t off = 0;
  auto alloc = [&](size_t bytes) -> char* {
    char* p = ws + off;
    off += (bytes + 255) & ~(size_t)255;
    return p;
  };
  unsigned short* xb = (unsigned short*)alloc((size_t)NND * HID * 2);          // 25.6 MB
  unsigned short* wp = (unsigned short*)alloc((size_t)NT * 4 * HID * MS * 2);  // 0.5 MB
  int* counts   = (int*)alloc((size_t)2 * NND * 4);                            // max 2 windows
  int* offsets  = (int*)alloc((size_t)(2 * NND + 1) * 4);
  int* cursor   = (int*)alloc((size_t)2 * NND * 4);
  int* bsum     = (int*)alloc(1024 * 4);
  int* edata    = (int*)alloc((size_t)TOTE * 4);                               // 2.4 MB
  float* denom  = (float*)alloc((size_t)NND * NHD * 4);                        // 3.2 MB

  size_t avail = (ws_size > off) ? (ws_size - off) : 0;
  const size_t perType = 4 * SEL * 2;  // Q,K,Ms,Mt for one type = 102.4 MB
  int TPH = (avail >= 4 * perType) ? 4 : 2;   // ws known >= ~257 MB from r2-r16
  int tshift = (TPH == 4) ? 2 : 1;
  int NWIN = NT / TPH;
  int ntot = NWIN * NND;
  unsigned short* region = (unsigned short*)(ws + off);
  unsigned short* bufQ  = region;
  unsigned short* bufK  = region + (size_t)TPH * SEL;
  unsigned short* bufMs = region + (size_t)2 * TPH * SEL;
  unsigned short* bufMt = region + (size_t)3 * TPH * SEL;

  hipMemsetAsync(counts, 0, (size_t)ntot * 4, stream);

  k_convert_x<<<(NND * HID) / (256 * 4), 256, 0, stream>>>(x, xb);
  k_pack_w<<<(NT * 4 * HID * MS) / 256, 256, 0, stream>>>(Wq, Wk, Wm, wp);

  const int NBS = (ntot + 255) / 256;  // <= 782, fits 1024-thread scan_mid
  k_hist<<<(TOTE + 255) / 256, 256, 0, stream>>>(adj, counts, tshift);
  k_blocksum<<<NBS, 256, 0, stream>>>(counts, bsum, ntot);
  k_scan_mid<<<1, 1024, 0, stream>>>(bsum, NBS, offsets, ntot);
  k_scan_add<<<NBS, 256, 0, stream>>>(counts, bsum, offsets, cursor, ntot);
  k_scatter<<<(TOTE + 255) / 256, 256, 0, stream>>>(adj, cursor, edata, tshift);

  const int nchunks = (NND + 127) / 128;   // 782
  const int cpx = (nchunks + 7) / 8;       // 98 chunks per XCD
  const int ngrid2 = (NND / 2 + 3) / 4;    // 12500 (2 nodes per wave)

  for (int w = 0; w < NWIN; w++) {
    int tlo = w * TPH;
    int npass = TPH * 4;
    int pgrid = 8 * cpx * npass;
    k_projF<<<pgrid, 256, 0, stream>>>(xb, wp, bm, bufQ, bufK, bufMs, bufMt,
                                       tlo, npass, cpx);
    if (TPH == 2)
      k_edge<2><<<ngrid2, 256, 0, stream>>>(edata, offsets + (size_t)w * NND,
                                            bufQ, bufK, bufMs, bufMt, out, denom,
                                            w == 0 ? 1 : 0, (w == NWIN - 1) ? 1 : 0);
    else
      k_edge<4><<<ngrid2, 256, 0, stream>>>(edata, offsets + (size_t)w * NND,
                                            bufQ, bufK, bufMs, bufMt, out, denom,
                                            w == 0 ? 1 : 0, (w == NWIN - 1) ? 1 : 0);
  }
}